// Round 13
// baseline (136.895 us; speedup 1.0000x reference)
//
#include <hip/hip_runtime.h>
#include <math.h>

#define TT 1024   // tokens
#define HH 1024   // hidden
#define MM 512    // moe intermediate
#define NE 16     // routed experts (e == NE -> shared expert)
// TOP_K = 2, SCALE = 2.5, NORM_TOPK = true

typedef _Float16 f16;
typedef _Float16 f16x4 __attribute__((ext_vector_type(4)));
typedef _Float16 f16x8 __attribute__((ext_vector_type(8)));
typedef float f32x4 __attribute__((ext_vector_type(4)));

#define GLL(g, l) __builtin_amdgcn_global_load_lds(                         \
    (const __attribute__((address_space(1))) void*)(g),                     \
    (__attribute__((address_space(3))) void*)(l), 16, 0, 0)
#define SB() __builtin_amdgcn_sched_barrier(0)
#define WAITVM(N) { SB(); asm volatile("s_waitcnt vmcnt(" #N ")"); SB(); }
#define BARRIER() __builtin_amdgcn_s_barrier()

// ---------------- pack x -> f16 ----------------
__global__ __launch_bounds__(256) void pack_k(const float* __restrict__ x, f16* __restrict__ xh)
{
    const int i = (blockIdx.x * 256 + threadIdx.x) * 4;
    float4 v = *(const float4*)(x + i);
    f16x4 h = { (f16)v.x, (f16)v.y, (f16)v.z, (f16)v.w };
    *(f16x4*)(xh + i) = h;
}

// ---------------- router ----------------
__global__ __launch_bounds__(256) void router_k(
    const float* __restrict__ x, const float* __restrict__ gate_w,
    int* __restrict__ counts, int* __restrict__ token_list, float* __restrict__ weight_list)
{
    const int wave = threadIdx.x >> 6;
    const int lane = threadIdx.x & 63;
    const int t = (blockIdx.x << 2) + wave;
    const float* xr = x + (size_t)t * HH;
    float xv[16];
#pragma unroll
    for (int i = 0; i < 16; ++i) xv[i] = xr[lane + (i << 6)];
    float sc[NE];
#pragma unroll
    for (int e = 0; e < NE; ++e) {
        const float* gr = gate_w + e * HH;
        float acc = 0.f;
#pragma unroll
        for (int i = 0; i < 16; ++i) acc = fmaf(xv[i], gr[lane + (i << 6)], acc);
#pragma unroll
        for (int off = 32; off > 0; off >>= 1) acc += __shfl_down(acc, off, 64);
        sc[e] = acc;
    }
    if (lane == 0) {
        float l1 = -1e30f, l2 = -1e30f; int i1 = 0, i2 = 0;
#pragma unroll
        for (int e = 0; e < NE; ++e) {
            float v = sc[e];
            if (v > l1) { l2 = l1; i2 = i1; l1 = v; i1 = e; }
            else if (v > l2) { l2 = v; i2 = e; }
        }
        float w1 = 1.f / (1.f + __expf(-l1));
        float w2 = 1.f / (1.f + __expf(-l2));
        const float inv = 2.5f / (w1 + w2 + 1e-20f);
        w1 *= inv; w2 *= inv;
        int s1 = atomicAdd(&counts[i1], 1);
        token_list[i1 * TT + s1] = t;
        weight_list[i1 * TT + s1] = w1;
        int s2 = atomicAdd(&counts[i2], 1);
        token_list[i2 * TT + s2] = t;
        weight_list[i2 * TT + s2] = w2;
    }
}

__global__ void prefix_k(const int* __restrict__ counts, int* __restrict__ offs)
{
    if (threadIdx.x == 0 && blockIdx.x == 0) {
        int acc = 0;
#pragma unroll
        for (int e = 0; e < NE; ++e) { offs[e] = acc; acc += counts[e]; }
        offs[NE] = acc;
    }
}

// ================= fused gate/up =================
// XCD-clustered 1D grid (as r12). BM=64, BN=32, BK=64.
// A: direct global->VGPR f16 b128 (L2-resident xh), loaded 2 phases ahead into
//    3 rotating literal register sets, issued BEFORE B's GLL group (FIFO: the
//    A-dependency wait then never forces younger B loads to drain).
// B: GLL fp32, TRIPLE-buffered LDS, one barrier/phase, WAITVM(4) counted.

#define GU_ALOAD(SL, T2) {                                                  \
    aA##SL##_[0] = *(const f16x8*)(pa0 + ((T2) << 6));                      \
    aA##SL##_[1] = *(const f16x8*)(pa0 + ((T2) << 6) + 32);                 \
    aA##SL##_[2] = *(const f16x8*)(pa1 + ((T2) << 6));                      \
    aA##SL##_[3] = *(const f16x8*)(pa1 + ((T2) << 6) + 32); }

#define GU_BISSUE(K0, BG, BU) {                                             \
    _Pragma("unroll") for (int i = 0; i < 2; ++i) {                         \
        GLL(pBg[i] + (size_t)(K0) * MM, &BG[(w << 4) + 8*i][0]);            \
        GLL(pBu[i] + (size_t)(K0) * MM, &BU[(w << 4) + 8*i][0]); } }

#define GU_COMP(SU, BG, BU) {                                               \
    _Pragma("unroll") for (int h = 0; h < 2; ++h) {                         \
        const int kb = (h << 5) + (lg << 3);                                \
        const int bc = (wn + lm) ^ ((lg & 1) << 4);                         \
        f16x8 bg, bu;                                                       \
        _Pragma("unroll") for (int j = 0; j < 8; ++j) {                     \
            bg[j] = (f16)BG[kb + j][bc]; bu[j] = (f16)BU[kb + j][bc]; }     \
        _Pragma("unroll") for (int f = 0; f < 2; ++f) {                     \
            accg[f] = __builtin_amdgcn_mfma_f32_16x16x32_f16(aA##SU##_[2*f+h], bg, accg[f], 0, 0, 0); \
            accu[f] = __builtin_amdgcn_mfma_f32_16x16x32_f16(aA##SU##_[2*f+h], bu, accu[f], 0, 0, 0); } } }

// phase T: wait my tile-T B group (issued T-2; leaves T-1's group + newer A in
// flight), barrier (publishes LDS; frees buf (T+2)%3 last read at T-1), load
// A(T+2) into set (T+2)%3, issue B(T+2) into buf (T+2)%3, compute tile T.
#define GU_PH(T, SU, SL, VC) {                                              \
    WAITVM(VC)                                                              \
    BARRIER();                                                              \
    if ((T) + 2 < 16) {                                                     \
        GU_ALOAD(SL, (T)+2)                                                 \
        GU_BISSUE(((T)+2) << 6, Bg##SL, Bu##SL)                             \
    }                                                                       \
    GU_COMP(SU, Bg##SU, Bu##SU) }

__global__ __launch_bounds__(256) void gu_k(
    const f16* __restrict__ xh,
    const float* __restrict__ w_gate, const float* __restrict__ w_up,
    const float* __restrict__ ws_gate, const float* __restrict__ ws_up,
    const int* __restrict__ counts, const int* __restrict__ offs,
    const int* __restrict__ token_list, f16* __restrict__ rinter)
{
    const int F = blockIdx.x;
    const int Q = F & 7;
    const int J = F >> 3;
    int e, tile;
    if (J < 512) { e = Q + ((J >> 8) << 3); tile = J & 255; }
    else         { e = NE; tile = (Q << 5) + (J - 512); }
    const int n0 = (tile & 15) << 5;
    const int r0 = (tile >> 4) << 6;

    int cnt, slot0;
    const float *wgp, *wup;
    if (e < NE) {
        cnt = counts[e]; slot0 = offs[e];
        wgp = w_gate + (size_t)e * HH * MM;
        wup = w_up   + (size_t)e * HH * MM;
    } else {
        cnt = TT; slot0 = 2 * TT;
        wgp = ws_gate; wup = ws_up;
    }
    if (r0 >= cnt) return;

    __shared__ float Bg0[64][32], Bg1[64][32], Bg2[64][32];
    __shared__ float Bu0[64][32], Bu1[64][32], Bu2[64][32];
    __shared__ int toks[64];

    const int tid = threadIdx.x;
    if (tid < 64) {
        int i = r0 + tid; if (i >= cnt) i = cnt - 1;
        toks[tid] = (e < NE) ? token_list[e * TT + i] : i;
    }
    __syncthreads();

    const int w = tid >> 6, lane = tid & 63;
    const int lm = lane & 15, lg = lane >> 4;
    const int wm = (w >> 1) << 5, wn = (w & 1) << 4;

    // A row pointers (f=0,1), direct from packed f16 x
    const f16* pa0 = xh + (size_t)toks[wm + lm]      * HH + (lg << 3);
    const f16* pa1 = xh + (size_t)toks[wm + 16 + lm] * HH + (lg << 3);

    // B staging pointers (r10-verified layout, swizzle folded into source)
    const float* pBg[2]; const float* pBu[2];
#pragma unroll
    for (int i = 0; i < 2; ++i) {
        int kr = (w << 4) + 8*i + (lane >> 3);
        int sg = 4 * ((lane & 7) ^ ((i & 1) << 2));
        pBg[i] = wgp + (size_t)kr * MM + n0 + sg;
        pBu[i] = wup + (size_t)kr * MM + n0 + sg;
    }

    f32x4 accg[2] = {}, accu[2] = {};
    f16x8 aA0_[4], aA1_[4], aA2_[4];

    // prologue: tiles 0,1 (A-regs + B in flight)
    GU_ALOAD(0, 0) GU_BISSUE(0, Bg0, Bu0)
    GU_ALOAD(1, 1) GU_BISSUE(1 << 6, Bg1, Bu1)

    GU_PH(0, 0, 2, 4)  GU_PH(1, 1, 0, 4)  GU_PH(2, 2, 1, 4)  GU_PH(3, 0, 2, 4)
    GU_PH(4, 1, 0, 4)  GU_PH(5, 2, 1, 4)  GU_PH(6, 0, 2, 4)  GU_PH(7, 1, 0, 4)
    GU_PH(8, 2, 1, 4)  GU_PH(9, 0, 2, 4)  GU_PH(10, 1, 0, 4) GU_PH(11, 2, 1, 4)
    GU_PH(12, 0, 2, 4) GU_PH(13, 1, 0, 4) GU_PH(14, 2, 1, 4) GU_PH(15, 0, 2, 0)

    // epilogue: silu(g)*u -> f16; C/D: col=lane&15, row=(lane>>4)*4+reg
#pragma unroll
    for (int fi = 0; fi < 2; ++fi)
#pragma unroll
        for (int rr = 0; rr < 4; ++rr) {
            const int m = wm + (fi << 4) + (lg << 2) + rr;
            if (r0 + m < cnt) {
                float g = accg[fi][rr], u = accu[fi][rr];
                float s = g / (1.f + __expf(-g));
                rinter[(size_t)(slot0 + r0 + m) * MM + n0 + wn + lm] = (f16)(s * u);
            }
        }
}

// ================= down: out[token] += weight * (rinter @ Wd) =================
// Same structure: A = rinter f16 direct->VGPR (3 sets), B = Wd fp32 GLL tbuf.

#define DN_ALOAD(SL, T2) {                                                  \
    aD##SL##_[0] = *(const f16x8*)(pa0 + ((T2) << 6));                      \
    aD##SL##_[1] = *(const f16x8*)(pa0 + ((T2) << 6) + 32);                 \
    aD##SL##_[2] = *(const f16x8*)(pa1 + ((T2) << 6));                      \
    aD##SL##_[3] = *(const f16x8*)(pa1 + ((T2) << 6) + 32); }

#define DN_BISSUE(K0, BS) {                                                 \
    _Pragma("unroll") for (int i = 0; i < 2; ++i)                           \
        GLL(pb[i] + (size_t)(K0) * HH, &BS[(w << 4) + 8*i][0]); }

#define DN_COMP(SU, BS) {                                                   \
    _Pragma("unroll") for (int h = 0; h < 2; ++h) {                         \
        const int kb = (h << 5) + (lg << 3);                                \
        const int bc = (wn + lm) ^ ((lg & 1) << 4);                         \
        f16x8 bv;                                                           \
        _Pragma("unroll") for (int j = 0; j < 8; ++j) bv[j] = (f16)BS[kb + j][bc]; \
        _Pragma("unroll") for (int f = 0; f < 2; ++f)                       \
            acc[f] = __builtin_amdgcn_mfma_f32_16x16x32_f16(aD##SU##_[2*f+h], bv, acc[f], 0, 0, 0); } }

#define DN_PH(T, SU, SL, VC) {                                              \
    WAITVM(VC)                                                              \
    BARRIER();                                                              \
    if ((T) + 2 < 8) {                                                      \
        DN_ALOAD(SL, (T)+2)                                                 \
        DN_BISSUE(((T)+2) << 6, Bs##SL)                                     \
    }                                                                       \
    DN_COMP(SU, Bs##SU) }

__global__ __launch_bounds__(256) void down_k(
    const f16* __restrict__ rinter,
    const float* __restrict__ w_down, const float* __restrict__ ws_down,
    const int* __restrict__ counts, const int* __restrict__ offs,
    const int* __restrict__ token_list, const float* __restrict__ weight_list,
    float* __restrict__ out)
{
    const int F = blockIdx.x;
    const int Q = F & 7;
    const int J = F >> 3;
    int e, tile;
    if (J < 1024) { e = Q + ((J >> 9) << 3); tile = J & 511; }
    else          { e = NE; tile = (Q << 6) + (J - 1024); }
    const int n0 = (tile & 31) << 5;   // of HH
    const int r0 = (tile >> 5) << 6;

    int cnt, slot0; const float* wdp;
    if (e < NE) { cnt = counts[e]; slot0 = offs[e]; wdp = w_down + (size_t)e * MM * HH; }
    else        { cnt = TT; slot0 = 2 * TT; wdp = ws_down; }
    if (r0 >= cnt) return;

    __shared__ float Bs0[64][32], Bs1[64][32], Bs2[64][32];

    const int tid = threadIdx.x;
    const int w = tid >> 6, lane = tid & 63;
    const int lm = lane & 15, lg = lane >> 4;
    const int wm = (w >> 1) << 5, wn = (w & 1) << 4;

    const f16* pa0 = rinter + (size_t)(slot0 + r0 + wm + lm)      * MM + (lg << 3);
    const f16* pa1 = rinter + (size_t)(slot0 + r0 + wm + 16 + lm) * MM + (lg << 3);

    const float* pb[2];
#pragma unroll
    for (int i = 0; i < 2; ++i) {
        int kr = (w << 4) + 8*i + (lane >> 3);
        pb[i] = wdp + (size_t)kr * HH + n0 + 4 * ((lane & 7) ^ ((i & 1) << 2));
    }

    f32x4 acc[2] = {};
    f16x8 aD0_[4], aD1_[4], aD2_[4];

    DN_ALOAD(0, 0) DN_BISSUE(0, Bs0)
    DN_ALOAD(1, 1) DN_BISSUE(1 << 6, Bs1)

    DN_PH(0, 0, 2, 2) DN_PH(1, 1, 0, 2) DN_PH(2, 2, 1, 2) DN_PH(3, 0, 2, 2)
    DN_PH(4, 1, 0, 2) DN_PH(5, 2, 1, 2) DN_PH(6, 0, 2, 2) DN_PH(7, 1, 0, 0)

#pragma unroll
    for (int fi = 0; fi < 2; ++fi)
#pragma unroll
        for (int rr = 0; rr < 4; ++rr) {
            const int m = wm + (fi << 4) + (lg << 2) + rr;
            const int row = r0 + m;
            if (row < cnt) {
                int t; float wt;
                if (e < NE) { t = token_list[e * TT + row]; wt = weight_list[e * TT + row]; }
                else        { t = row; wt = 1.f; }
                atomicAdd(&out[(size_t)t * HH + n0 + wn + lm], wt * acc[fi][rr]);
            }
        }
}

extern "C" void kernel_launch(void* const* d_in, const int* in_sizes, int n_in,
                              void* d_out, int out_size, void* d_ws, size_t ws_size,
                              hipStream_t stream)
{
    const float* x       = (const float*)d_in[0];
    const float* gate_w  = (const float*)d_in[1];
    const float* w_gate  = (const float*)d_in[2];
    const float* w_up    = (const float*)d_in[3];
    const float* w_down  = (const float*)d_in[4];
    const float* ws_gate = (const float*)d_in[5];
    const float* ws_up   = (const float*)d_in[6];
    const float* ws_down = (const float*)d_in[7];
    float* out = (float*)d_out;

    // ws: counts[16]|offs[17]|pad 64 ints | token_list 16K | weight_list 16K |
    // rinter f16 [3072][512] | xh f16 [1024][1024]
    int* counts = (int*)d_ws;
    int* offs = counts + 16;
    int* token_list = counts + 64;
    float* weight_list = (float*)(counts + 64 + NE * TT);
    f16* rinter = (f16*)(counts + 64 + 2 * NE * TT);
    f16* xh = rinter + (size_t)3072 * MM;

    hipMemsetAsync(counts, 0, 64, stream);
    hipMemsetAsync(out, 0, (size_t)TT * HH * sizeof(float), stream);
    pack_k<<<dim3(TT * HH / 1024), 256, 0, stream>>>(x, xh);
    router_k<<<dim3(TT / 4), 256, 0, stream>>>(x, gate_w, counts, token_list, weight_list);
    prefix_k<<<1, 64, 0, stream>>>(counts, offs);
    gu_k<<<dim3(8 * 544), 256, 0, stream>>>(
        xh, w_gate, w_up, ws_gate, ws_up, counts, offs, token_list, rinter);
    down_k<<<dim3(8 * 1088), 256, 0, stream>>>(
        rinter, w_down, ws_down, counts, offs, token_list, weight_list, out);
}